// Round 1
// baseline (374.076 us; speedup 1.0000x reference)
//
#include <hip/hip_runtime.h>
#include <hip/hip_bf16.h>
#include <stdint.h>

#define DD 128
#define RW 0.001f

typedef __attribute__((ext_vector_type(4))) float f32x4;
typedef __attribute__((ext_vector_type(8))) short bf16x8;

// pack two f32 into one u32 of 2 bf16 (truncation) via v_perm_b32
static __device__ __forceinline__ uint32_t pack2(float lo, float hi){
  return __builtin_amdgcn_perm(__float_as_uint(hi), __float_as_uint(lo), 0x07060302u);
}

static __device__ __forceinline__ ushort rne_bf16(float f){
  uint32_t u = __float_as_uint(f);
  return (ushort)((u + 0x7fffu + ((u >> 16) & 1u)) >> 16);
}

// ---- K1: fold weights -------------------------------------------------
__global__ void prep_weights(const float* __restrict__ Wl, const float* __restrict__ bl,
                             const float* __restrict__ Wr, const float* __restrict__ Wres,
                             const float* __restrict__ bres,
                             ushort* __restrict__ Wlb, ushort* __restrict__ Wcb,
                             float* __restrict__ bc){
  int i = blockIdx.x * 256 + threadIdx.x;   // 0..16383
  float wl = RW * Wl[i];
  float wc = RW * Wr[i] + (1.f - RW) * Wres[i];
  Wlb[i] = rne_bf16(wl);
  Wcb[i] = rne_bf16(wc);
  if (i < DD) bc[i] = RW * bl[i] + (1.f - RW) * bres[i];
}

// ---- K2: histogram of dst ---------------------------------------------
__global__ void hist(const int* __restrict__ dst, int* __restrict__ deg, int E){
  int e = blockIdx.x * 256 + threadIdx.x;
  if (e < E) atomicAdd(&deg[dst[e]], 1);
}

// ---- K3a/b/c: exclusive scan over deg ---------------------------------
__global__ __launch_bounds__(1024) void scan1(const int* __restrict__ deg,
                                              int* __restrict__ offs,
                                              int* __restrict__ bsum, int n){
  __shared__ int sm[1024];
  int tid = threadIdx.x;
  int i = blockIdx.x * 1024 + tid;
  int v = (i < n) ? deg[i] : 0;
  int val = v;
  sm[tid] = val; __syncthreads();
  for (int off = 1; off < 1024; off <<= 1){
    int t = (tid >= off) ? sm[tid - off] : 0;
    __syncthreads();
    val += t; sm[tid] = val;
    __syncthreads();
  }
  if (i < n) offs[i] = val - v;
  if (tid == 1023) bsum[blockIdx.x] = val;
}

__global__ void scan2(int* __restrict__ bsum, int nb){  // 1 block, 128 threads, nb<=128
  __shared__ int sm[128];
  int tid = threadIdx.x;
  int v = (tid < nb) ? bsum[tid] : 0;
  int val = v;
  sm[tid] = val; __syncthreads();
  for (int off = 1; off < 128; off <<= 1){
    int t = (tid >= off) ? sm[tid - off] : 0;
    __syncthreads();
    val += t; sm[tid] = val;
    __syncthreads();
  }
  if (tid < nb) bsum[tid] = val - v;
}

__global__ __launch_bounds__(1024) void scan3(int* __restrict__ offs, int* __restrict__ cur,
                                              const int* __restrict__ bsum, int n){
  int i = blockIdx.x * 1024 + threadIdx.x;
  if (i < n){
    int v = offs[i] + bsum[blockIdx.x];
    offs[i] = v;
    cur[i]  = v;
  }
}

// ---- K4: CSR fill ------------------------------------------------------
__global__ void fillk(const int* __restrict__ src, const int* __restrict__ dst,
                      int* __restrict__ cur, int* __restrict__ sorted, int E){
  int e = blockIdx.x * 256 + threadIdx.x;
  if (e < E){
    int p = atomicAdd(&cur[dst[e]], 1);
    sorted[p] = src[e];
  }
}

// ---- K5: fused dual GEMM: y = bf16(x @ Wl'.T), out = x @ Wc.T + bc -----
// tile 128 rows x 256 cols, 8 waves (2x4), per-wave 64x64, K=128
__global__ __launch_bounds__(512) void gemm_fused(
    const float* __restrict__ x, const ushort* __restrict__ Wlb,
    const ushort* __restrict__ Wcb, const float* __restrict__ bc,
    ushort* __restrict__ y, float* __restrict__ out, int M)
{
  __shared__ char sW[2][32768];   // two 128x128 bf16 matrices, XOR-swizzled rows
  int tid = threadIdx.x;

  #pragma unroll
  for (int m = 0; m < 2; m++){
    const char* srcw = (const char*)(m ? Wcb : Wlb);
    #pragma unroll
    for (int c = 0; c < 1; c++){ }
    #pragma unroll
    for (int c = 0; c < 4; c++){
      int bo  = tid * 64 + c * 16;          // 512 thr * 64B = 32768B
      int row = bo >> 8;
      int kb  = bo & 255;
      int s   = (row << 8) | (kb ^ ((row & 7) << 4));
      *(uint4*)(&sW[m][s]) = *(const uint4*)(srcw + bo);
    }
  }
  __syncthreads();

  int lane = tid & 63, w = tid >> 6;
  int wr = w >> 2, wc = w & 3;              // wr 0..1 (rows), wc 0..3 (64-col stripes)
  int l15 = lane & 15, lhi = lane >> 4;
  int rowbase = blockIdx.x * 128 + wr * 64;
  int mtx = wc >> 1;                        // 0 -> Wl' (y), 1 -> Wc (out)
  int colbase = (wc & 1) * 64;

  f32x4 acc[4][4];
  #pragma unroll
  for (int a = 0; a < 4; a++)
    #pragma unroll
    for (int b = 0; b < 4; b++) acc[a][b] = (f32x4){0.f,0.f,0.f,0.f};

  int nodes[4];
  #pragma unroll
  for (int rt = 0; rt < 4; rt++){
    int nd = rowbase + rt * 16 + l15;
    nodes[rt] = (nd < M) ? nd : (M - 1);
  }

  #pragma unroll
  for (int ks = 0; ks < 4; ks++){
    bf16x8 afr[4];
    #pragma unroll
    for (int rt = 0; rt < 4; rt++){
      const float* ap = x + (size_t)nodes[rt] * DD + ks * 32 + lhi * 8;
      f32x4 f0 = *(const f32x4*)ap;
      f32x4 f1 = *(const f32x4*)(ap + 4);
      union { uint32_t u[4]; bf16x8 v; } cv;
      cv.u[0] = pack2(f0[0], f0[1]);
      cv.u[1] = pack2(f0[2], f0[3]);
      cv.u[2] = pack2(f1[0], f1[1]);
      cv.u[3] = pack2(f1[2], f1[3]);
      afr[rt] = cv.v;
    }
    int kb = (ks * 32 + lhi * 8) * 2;
    #pragma unroll
    for (int ct = 0; ct < 4; ct++){
      int colm = colbase + ct * 16 + l15;
      int s = (colm << 8) | (kb ^ ((colm & 7) << 4));
      bf16x8 bfr = *(const bf16x8*)(&sW[mtx][s]);
      #pragma unroll
      for (int rt = 0; rt < 4; rt++)
        acc[rt][ct] = __builtin_amdgcn_mfma_f32_16x16x32_bf16(afr[rt], bfr, acc[rt][ct], 0, 0, 0);
    }
  }

  if (mtx == 1){
    #pragma unroll
    for (int ct = 0; ct < 4; ct++){
      int col = colbase + ct * 16 + l15;
      float bias = bc[col];
      #pragma unroll
      for (int rt = 0; rt < 4; rt++){
        #pragma unroll
        for (int i = 0; i < 4; i++){
          int row = rowbase + rt * 16 + lhi * 4 + i;
          if (row < M) out[(size_t)row * DD + col] = acc[rt][ct][i] + bias;
        }
      }
    }
  } else {
    #pragma unroll
    for (int ct = 0; ct < 4; ct++){
      int col = colbase + ct * 16 + l15;
      #pragma unroll
      for (int rt = 0; rt < 4; rt++){
        #pragma unroll
        for (int i = 0; i < 4; i++){
          int row = rowbase + rt * 16 + lhi * 4 + i;
          if (row < M) y[(size_t)row * DD + col] = (ushort)(__float_as_uint(acc[rt][ct][i]) >> 16);
        }
      }
    }
  }
}

// ---- K6: gather-aggregate y rows per node, add into out ----------------
__global__ __launch_bounds__(256) void agg_add(
    const ushort* __restrict__ y, const int* __restrict__ sorted,
    const int* __restrict__ offs, const int* __restrict__ deg,
    float* __restrict__ out, int N)
{
  int wid = (int)((blockIdx.x * 256 + threadIdx.x) >> 6);
  if (wid >= N) return;
  int lane = threadIdx.x & 63;
  int start = offs[wid], cnt = deg[wid];
  float a0 = 0.f, a1 = 0.f;
  int i = 0;
  for (; i + 2 <= cnt; i += 2){
    int s0 = sorted[start + i];
    int s1 = sorted[start + i + 1];
    uint32_t v0 = *(const uint32_t*)(y + (size_t)s0 * DD + lane * 2);
    uint32_t v1 = *(const uint32_t*)(y + (size_t)s1 * DD + lane * 2);
    a0 += __uint_as_float(v0 << 16) + __uint_as_float(v1 << 16);
    a1 += __uint_as_float(v0 & 0xffff0000u) + __uint_as_float(v1 & 0xffff0000u);
  }
  if (i < cnt){
    int s0 = sorted[start + i];
    uint32_t v0 = *(const uint32_t*)(y + (size_t)s0 * DD + lane * 2);
    a0 += __uint_as_float(v0 << 16);
    a1 += __uint_as_float(v0 & 0xffff0000u);
  }
  float2* p = (float2*)(out + (size_t)wid * DD + lane * 2);
  float2 t = *p;
  t.x += a0; t.y += a1;
  *p = t;
}

extern "C" void kernel_launch(void* const* d_in, const int* in_sizes, int n_in,
                              void* d_out, int out_size, void* d_ws, size_t ws_size,
                              hipStream_t stream) {
  const float* x    = (const float*)d_in[0];
  const int*   ei   = (const int*)d_in[1];
  const float* Wl   = (const float*)d_in[2];
  const float* bl   = (const float*)d_in[3];
  const float* Wr   = (const float*)d_in[4];
  const float* Wres = (const float*)d_in[5];
  const float* bres = (const float*)d_in[6];
  float* out = (float*)d_out;

  int M = in_sizes[0] / DD;        // 100000 nodes
  int E = in_sizes[1] / 2;         // 1600000 edges
  const int* esrc = ei;
  const int* edst = ei + E;

  char* w = (char*)d_ws;
  size_t off = 0;
  ushort* y    = (ushort*)(w + off); off += (size_t)M * DD * 2;       // 25.6 MB
  ushort* Wlb  = (ushort*)(w + off); off += DD * DD * 2;
  ushort* Wcb  = (ushort*)(w + off); off += DD * DD * 2;
  float*  bc   = (float*) (w + off); off += 512;
  int*    deg  = (int*)   (w + off); off += sizeof(int) * (size_t)M;
  int*    offs = (int*)   (w + off); off += sizeof(int) * (size_t)M;
  int*    cur  = (int*)   (w + off); off += sizeof(int) * (size_t)M;
  int*    bsum = (int*)   (w + off); off += 1024;
  int*    sorted = (int*) (w + off);

  hipMemsetAsync(deg, 0, sizeof(int) * (size_t)M, stream);
  prep_weights<<<(DD * DD) / 256, 256, 0, stream>>>(Wl, bl, Wr, Wres, bres, Wlb, Wcb, bc);
  hist<<<(E + 255) / 256, 256, 0, stream>>>(edst, deg, E);
  int nb = (M + 1023) / 1024;
  scan1<<<nb, 1024, 0, stream>>>(deg, offs, bsum, M);
  scan2<<<1, 128, 0, stream>>>(bsum, nb);
  scan3<<<nb, 1024, 0, stream>>>(offs, cur, bsum, M);
  fillk<<<(E + 255) / 256, 256, 0, stream>>>(esrc, edst, cur, sorted, E);
  gemm_fused<<<(M + 127) / 128, 512, 0, stream>>>(x, Wlb, Wcb, bc, y, out, M);
  agg_add<<<((size_t)M * 64 + 255) / 256, 256, 0, stream>>>(y, sorted, offs, deg, out, M);
}